// Round 17
// baseline (85.765 us; speedup 1.0000x reference)
//
#include <hip/hip_runtime.h>
#include <math.h>
#include <stdint.h>

#define NN 7
#define HD 128
#define FIN 32
#define TPB 16           // 16 tokens per block; 4 waves, each owns 4 tokens
#define RPW 28           // rows per wave (4 tokens x 7 nodes)
#define LN_EPS 1e-5f
#define ALPHA 0.2f
#define NEG_CONST -9e15f
#define SCALE 0.08838834764831845f  // 128^-0.5

typedef __bf16 bf16x8 __attribute__((ext_vector_type(8)));
typedef float  f32x4  __attribute__((ext_vector_type(4)));

// intra-wave LDS ordering; sched_barrier stops hoisting past the wait (rule #18)
#define FENCE() do { asm volatile("s_waitcnt lgkmcnt(0)" ::: "memory"); \
                     __builtin_amdgcn_sched_barrier(0); } while (0)

__device__ __forceinline__ uint16_t f2bf_u(float f) {
    union { float f; uint32_t u; } v; v.f = f;
    uint32_t r = v.u + 0x7FFFu + ((v.u >> 16) & 1u);  // RNE
    return (uint16_t)(r >> 16);
}
__device__ __forceinline__ uint32_t pack2(float a, float b) {
    return (uint32_t)f2bf_u(a) | ((uint32_t)f2bf_u(b) << 16);
}
__device__ __forceinline__ float bflo(uint32_t u) {
    union { uint32_t q; float f; } v; v.q = u << 16; return v.f;
}
__device__ __forceinline__ float bfhi(uint32_t u) {
    union { uint32_t q; float f; } v; v.q = u & 0xffff0000u; return v.f;
}
__device__ __forceinline__ f32x4 unpk_lo(uint4 h) {   // bf16 pairs (x,y) -> 4 floats
    return (f32x4){bflo(h.x), bfhi(h.x), bflo(h.y), bfhi(h.y)};
}
__device__ __forceinline__ f32x4 unpk_hi(uint4 h) {   // bf16 pairs (z,w) -> 4 floats
    return (f32x4){bflo(h.z), bfhi(h.z), bflo(h.w), bfhi(h.w)};
}

// DPP lane-reduce: ctrl must be an ICE -> template parameter
template <int CTRL>
__device__ __forceinline__ float dpp_add(float v) {
    union { float f; int i; } a, r;
    a.f = v;
    r.i = __builtin_amdgcn_update_dpp(a.i, a.i, CTRL, 0xF, 0xF, false);
    return v + r.f;
}
__device__ __forceinline__ float sum16(float v) {
    v = dpp_add<0xB1>(v);    // quad_perm [1,0,3,2] : xor 1
    v = dpp_add<0x4E>(v);    // quad_perm [2,3,0,1] : xor 2
    v = dpp_add<0x124>(v);   // row_ror:4
    v = dpp_add<0x128>(v);   // row_ror:8
    return v;
}

// ws layout (bytes):
//  WpTp[896][32] bf16 @0 | W1Tp[128][128] bf16 @57344 | W2Tp[128][128] bf16 @90112
//  | vabp[2][2][128] f32 @122880 | bpp[896] f32 @124928 | gbp[2][2][128] f32 @128512
#define WS_W1T  57344
#define WS_W2T  90112
#define WS_VAB  122880
#define WS_BPP  124928
#define WS_GBP  128512

__global__ __launch_bounds__(256) void prep_weights(
    const float* __restrict__ Wp, const float* __restrict__ bp,
    const float* __restrict__ W1, const float* __restrict__ a1,
    const float* __restrict__ g1, const float* __restrict__ b1,
    const float* __restrict__ W2, const float* __restrict__ a2,
    const float* __restrict__ g2, const float* __restrict__ b2,
    uint16_t* __restrict__ WpT, uint16_t* __restrict__ W1T,
    uint16_t* __restrict__ W2T, float* __restrict__ vab,
    float* __restrict__ bpp, float* __restrict__ gbp)
{
    const int bid = blockIdx.x, tid = threadIdx.x;
    if (bid < 112) {                 // WpTp[sig(gc)][f] = Wp[f][gc]
        int idx = bid * 256 + tid;
        int gc = idx >> 5, f = idx & 31;
        int gcp = (gc & ~127) | (((gc & 15) << 3) | ((gc & 127) >> 4));
        WpT[gcp * 32 + f] = f2bf_u(Wp[(size_t)f * (NN * HD) + gc]);
    } else if (bid < 176) {          // W1Tp[c][sig(k)] = W1[k][c]
        int idx = (bid - 112) * 256 + tid;
        int c = idx >> 7, k = idx & 127;
        int kp = ((k & 15) << 3) | (k >> 4);
        W1T[c * 128 + kp] = f2bf_u(W1[(size_t)k * HD + c]);
    } else if (bid < 240) {          // W2Tp[c][sig(k)] = W2[k][c]
        int idx = (bid - 176) * 256 + tid;
        int c = idx >> 7, k = idx & 127;
        int kp = ((k & 15) << 3) | (k >> 4);
        W2T[c * 128 + kp] = f2bf_u(W2[(size_t)k * HD + c]);
    } else {
        // vabp[l][which][sig(j)] = sum_o W[j][o]*a[which*128+o]
        for (int d = tid; d < 512; d += 256) {
            int l = d >> 8, which = (d >> 7) & 1, j = d & 127;
            const float* W = l ? W2 : W1;
            const float* a = (l ? a2 : a1) + which * HD;
            const float* row = W + (size_t)j * HD;
            float acc = 0.f;
            #pragma unroll 8
            for (int o = 0; o < HD; o += 4) {
                f32x4 wv = *reinterpret_cast<const f32x4*>(&row[o]);
                acc += wv[0]*a[o] + wv[1]*a[o+1] + wv[2]*a[o+2] + wv[3]*a[o+3];
            }
            int jp = ((j & 15) << 3) | (j >> 4);
            vab[l * 256 + which * 128 + jp] = acc;
        }
        // bpp[sig_g(gc)] = bp[gc]
        for (int gc = tid; gc < NN * HD; gc += 256) {
            int gcp = (gc & ~127) | (((gc & 15) << 3) | ((gc & 127) >> 4));
            bpp[gcp] = bp[gc];
        }
        // gbp[l][{g,b}][sig(c)]
        for (int e = tid; e < 512; e += 256) {
            int l = e >> 8, which = (e >> 7) & 1, c = e & 127;
            const float* src = l ? (which ? b2 : g2) : (which ? b1 : g1);
            int cp = ((c & 15) << 3) | (c >> 4);
            gbp[l * 256 + which * 128 + cp] = src[c];
        }
    }
}

__global__ __launch_bounds__(256, 3) void gat_fused(
    const float* __restrict__ x, const float* __restrict__ adj,
    const float* __restrict__ bpp,
    const uint16_t* __restrict__ WpT, const uint16_t* __restrict__ W1T,
    const uint16_t* __restrict__ W2T, const float* __restrict__ vab,
    const float* __restrict__ gbp,
    float* __restrict__ out, int BT)
{
    // bf16 residual h, sigma-permuted cols; per-wave slice = 28 rows (4 tokens)
    // 30464 B/block -> 3 blocks/CU = 12 waves/CU (3/SIMD); 170 reg cap -> no spill
    __shared__ __align__(16) uint16_t h_s[4][RPW][136];

    const int tid  = threadIdx.x;
    const int lane = tid & 63;
    const int wave = tid >> 6;
    const int frow = lane & 15;
    const int kgrp = lane >> 4;
    const int kb   = kgrp * 8;
    const int t0   = blockIdx.x * TPB;

    // per-lane softmax-row identity: row0 = frow (clamped); tile1 row = 14+row0
    const int row0 = (frow > 13) ? 13 : frow;
    const int tb   = (row0 >= NN) ? 1 : 0;      // token-in-pair
    const int np   = row0 - tb * NN;            // node (same for both tiles)

    uint32_t amask = 0;
    #pragma unroll
    for (int j = 0; j < NN; ++j)
        amask |= (adj[np * NN + j] > 0.f) ? (1u << j) : 0u;

    // ---- B-frag: x for the block's 16 tokens (B col = token = frow) ----
    bf16x8 bx;
    {
        union { bf16x8 v; uint32_t u[4]; } bu;
        bu.u[0] = bu.u[1] = bu.u[2] = bu.u[3] = 0;
        int tok = t0 + frow;
        if (tok < BT) {
            f32x4 xa = *reinterpret_cast<const f32x4*>(&x[(size_t)tok * FIN + kb]);
            f32x4 xb = *reinterpret_cast<const f32x4*>(&x[(size_t)tok * FIN + kb + 4]);
            bu.u[0] = pack2(xa[0], xa[1]);
            bu.u[1] = pack2(xa[2], xa[3]);
            bu.u[2] = pack2(xb[0], xb[1]);
            bu.u[3] = pack2(xb[2], xb[3]);
        }
        bx = bu.v;
    }

    // ---- cooperative projection: 14 tiles/wave, all 16 B-cols used ----
    #pragma unroll 2
    for (int i = 0; i < 14; ++i) {
        int tile = wave * 14 + i;
        bf16x8 av = *reinterpret_cast<const bf16x8*>(WpT + (size_t)(tile * 16 + frow) * FIN + kb);
        f32x4 acc = {0.f, 0.f, 0.f, 0.f};
        acc = __builtin_amdgcn_mfma_f32_16x16x32_bf16(av, bx, acc, 0, 0, 0);
        int tok = t0 + frow;                 // C col = token, C row = out-col'
        if (tok < BT) {
            int gc0 = tile * 16 + kgrp * 4;  // 4 consecutive sigma-cols, same node
            f32x4 bias = *reinterpret_cast<const f32x4*>(&bpp[gc0]);
            f32x4 v = acc + bias;
            int n = gc0 >> 7, kk = gc0 & 127;
            uint2 uu = { pack2(v[0], v[1]), pack2(v[2], v[3]) };
            // token frow -> wave slice frow>>2, local row (frow&3)*7+n
            *reinterpret_cast<uint2*>(&h_s[frow >> 2][(frow & 3) * NN + n][kk]) = uu;
        }
    }
    __syncthreads();   // the only block barrier

    for (int l = 0; l < 2; ++l) {
        const uint16_t* __restrict__ WT  = l ? W2T : W1T;
        const float*    __restrict__ vv0 = vab + l * 256;
        const float*    __restrict__ ggp = gbp + l * 256;  // [0..127]=gamma', [128..255]=beta'

        // ---- phase A: f-dots, full 128-dot per lane, vector accumulate ----
        // lanes 0..27: f_src[row=lane]; lanes 32..59: f_dst[row=lane-32]
        float facc;
        {
            int which = lane >> 5;
            int rr = lane & 31; if (rr > RPW - 1) rr = RPW - 1;
            const uint32_t* hr = reinterpret_cast<const uint32_t*>(&h_s[wave][rr][0]);
            const f32x4* vp = reinterpret_cast<const f32x4*>(vv0 + which * HD);
            f32x4 a0 = {0,0,0,0}, a1 = {0,0,0,0};
            #pragma unroll
            for (int i2 = 0; i2 < 16; ++i2) {
                uint4 hv = *reinterpret_cast<const uint4*>(hr + i2 * 4);   // 8 bf16
                a0 += unpk_lo(hv) * vp[2 * i2];
                a1 += unpk_hi(hv) * vp[2 * i2 + 1];
            }
            f32x4 a = a0 + a1;
            facc = (a[0] + a[1]) + (a[2] + a[3]);
        }

        // ---- phase B: two softmax rows per lane (row0 tile0, 14+row0 tile1) ----
        float p0[NN], p1[NN];
        {
            float fs0 = __shfl(facc, row0, 64);
            float fs1 = __shfl(facc, 14 + row0, 64);
            float e0[NN], e1[NN];
            float mx0 = -INFINITY, mx1 = -INFINITY;
            #pragma unroll
            for (int j = 0; j < NN; ++j) {
                float fd0 = __shfl(facc, 32 + tb * NN + j, 64);
                float fd1 = __shfl(facc, 32 + 14 + tb * NN + j, 64);
                float v0 = fs0 + fd0, v1 = fs1 + fd1;
                v0 = (v0 > 0.f ? v0 : ALPHA * v0) * SCALE;
                v1 = (v1 > 0.f ? v1 : ALPHA * v1) * SCALE;
                bool ok = (amask >> j) & 1u;
                v0 = ok ? v0 : NEG_CONST;
                v1 = ok ? v1 : NEG_CONST;
                e0[j] = v0; mx0 = fmaxf(mx0, v0);
                e1[j] = v1; mx1 = fmaxf(mx1, v1);
            }
            float s0 = 0.f, s1 = 0.f;
            #pragma unroll
            for (int j = 0; j < NN; ++j) {
                e0[j] = __expf(e0[j] - mx0); s0 += e0[j];
                e1[j] = __expf(e1[j] - mx1); s1 += e1[j];
            }
            float i0 = 1.f / s0, i1 = 1.f / s1;
            #pragma unroll
            for (int j = 0; j < NN; ++j) { p0[j] = e0[j] * i0; p1[j] = e1[j] * i1; }
        }

        // ---- phase C: A-frags for both tiles, vector FMA on unpacked bf16 ----
        bf16x8 avA[4], avB[4];
        #pragma unroll
        for (int ks = 0; ks < 4; ++ks) {
            f32x4 ga0 = {0,0,0,0}, ga1 = {0,0,0,0};
            f32x4 gb0 = {0,0,0,0}, gb1 = {0,0,0,0};
            #pragma unroll
            for (int j = 0; j < NN; ++j) {
                uint4 hv = *reinterpret_cast<const uint4*>(&h_s[wave][tb * NN + j][ks * 32 + kb]);
                float pj = p0[j];
                ga0 += unpk_lo(hv) * pj;
                ga1 += unpk_hi(hv) * pj;
            }
            #pragma unroll
            for (int j = 0; j < NN; ++j) {
                uint4 hv = *reinterpret_cast<const uint4*>(&h_s[wave][14 + tb * NN + j][ks * 32 + kb]);
                float pj = p1[j];
                gb0 += unpk_lo(hv) * pj;
                gb1 += unpk_hi(hv) * pj;
            }
            union { bf16x8 v; uint32_t u[4]; } ba, bb;
            ba.u[0] = pack2(ga0[0], ga0[1]); ba.u[1] = pack2(ga0[2], ga0[3]);
            ba.u[2] = pack2(ga1[0], ga1[1]); ba.u[3] = pack2(ga1[2], ga1[3]);
            bb.u[0] = pack2(gb0[0], gb0[1]); bb.u[1] = pack2(gb0[2], gb0[3]);
            bb.u[2] = pack2(gb1[0], gb1[1]); bb.u[3] = pack2(gb1[2], gb1[3]);
            avA[ks] = ba.v; avB[ks] = bb.v;
        }

        // ---- phase D: two GEMM tiles share the B-frag loads (2x amortization) ----
        f32x4 C0[8], C1[8];
        #pragma unroll
        for (int ntl = 0; ntl < 8; ++ntl) {
            const uint16_t* bpg = WT + (size_t)(ntl * 16 + frow) * HD + kb;
            bf16x8 bv0 = *reinterpret_cast<const bf16x8*>(bpg);
            bf16x8 bv1 = *reinterpret_cast<const bf16x8*>(bpg + 32);
            bf16x8 bv2 = *reinterpret_cast<const bf16x8*>(bpg + 64);
            bf16x8 bv3 = *reinterpret_cast<const bf16x8*>(bpg + 96);
            f32x4 a0 = {0,0,0,0}, a1 = {0,0,0,0};
            a0 = __builtin_amdgcn_mfma_f32_16x16x32_bf16(avA[0], bv0, a0, 0, 0, 0);
            a1 = __builtin_amdgcn_mfma_f32_16x16x32_bf16(avB[0], bv0, a1, 0, 0, 0);
            a0 = __builtin_amdgcn_mfma_f32_16x16x32_bf16(avA[1], bv1, a0, 0, 0, 0);
            a1 = __builtin_amdgcn_mfma_f32_16x16x32_bf16(avB[1], bv1, a1, 0, 0, 0);
            a0 = __builtin_amdgcn_mfma_f32_16x16x32_bf16(avA[2], bv2, a0, 0, 0, 0);
            a1 = __builtin_amdgcn_mfma_f32_16x16x32_bf16(avB[2], bv2, a1, 0, 0, 0);
            a0 = __builtin_amdgcn_mfma_f32_16x16x32_bf16(avA[3], bv3, a0, 0, 0, 0);
            a1 = __builtin_amdgcn_mfma_f32_16x16x32_bf16(avB[3], bv3, a1, 0, 0, 0);
            C0[ntl] = a0; C1[ntl] = a1;
        }

        // ---- phase E: LayerNorm + residual; vector reduce + folded epilogue ----
        {
            f32x4 gv0 = *reinterpret_cast<const f32x4*>(ggp + frow * 8);
            f32x4 gv1 = *reinterpret_cast<const f32x4*>(ggp + frow * 8 + 4);
            f32x4 bt0 = *reinterpret_cast<const f32x4*>(ggp + 128 + frow * 8);
            f32x4 bt1 = *reinterpret_cast<const f32x4*>(ggp + 128 + frow * 8 + 4);
            #pragma unroll
            for (int tile = 0; tile < 2; ++tile) {
                const f32x4* C = tile ? C1 : C0;
                const int mbase = tile * 14;
                f32x4 s4 = C[0] + C[1];
                f32x4 q4 = C[0]*C[0] + C[1]*C[1];
                #pragma unroll
                for (int nt = 2; nt < 8; ++nt) { s4 += C[nt]; q4 += C[nt]*C[nt]; }
                #pragma unroll
                for (int r = 0; r < 4; ++r) {
                    float s  = sum16(s4[r]);
                    float sq = sum16(q4[r]);
                    float mean = s * (1.f / HD);
                    float var  = sq * (1.f / HD) - mean * mean;
                    float rinv = rsqrtf(var + LN_EPS);
                    int m = kgrp * 4 + r;
                    if (m < 14) {
                        f32x4 coef0 = gv0 * rinv, coef1 = gv1 * rinv;
                        f32x4 off0  = bt0 - coef0 * mean;
                        f32x4 off1  = bt1 - coef1 * mean;
                        uint16_t* hp = &h_s[wave][mbase + m][frow * 8];
                        uint4 hold = *reinterpret_cast<const uint4*>(hp);
                        f32x4 h0 = unpk_lo(hold) + off0;
                        f32x4 h1 = unpk_hi(hold) + off1;
                        h0[0] += C[0][r] * coef0[0];
                        h0[1] += C[1][r] * coef0[1];
                        h0[2] += C[2][r] * coef0[2];
                        h0[3] += C[3][r] * coef0[3];
                        h1[0] += C[4][r] * coef1[0];
                        h1[1] += C[5][r] * coef1[1];
                        h1[2] += C[6][r] * coef1[2];
                        h1[3] += C[7][r] * coef1[3];
                        uint4 w;
                        w.x = pack2(h0[0], h0[1]); w.y = pack2(h0[2], h0[3]);
                        w.z = pack2(h1[0], h1[1]); w.w = pack2(h1[2], h1[3]);
                        *reinterpret_cast<uint4*>(hp) = w;
                    }
                }
            }
        }
        FENCE();
    }

    // ---- out = mean over nodes; 4 tokens/wave; de-permute on store ----
    {
        int t_o = lane >> 4;            // 0..3
        int cq  = lane & 15;            // sigma col block cq*8..+7
        int tok = t0 + wave * 4 + t_o;
        if (tok < BT) {
            f32x4 s0 = {0,0,0,0}, s1 = {0,0,0,0};
            #pragma unroll
            for (int n = 0; n < NN; ++n) {
                uint4 hv = *reinterpret_cast<const uint4*>(&h_s[wave][t_o * NN + n][cq * 8]);
                s0 += unpk_lo(hv);
                s1 += unpk_hi(hv);
            }
            const float inv7 = 1.f / 7.f;
            s0 *= inv7; s1 *= inv7;
            float* ob = out + (size_t)tok * HD;
            // sigma col cp = cq*8+e  <->  orig c = e*16 + cq
            ob[0*16+cq] = s0[0]; ob[1*16+cq] = s0[1];
            ob[2*16+cq] = s0[2]; ob[3*16+cq] = s0[3];
            ob[4*16+cq] = s1[0]; ob[5*16+cq] = s1[1];
            ob[6*16+cq] = s1[2]; ob[7*16+cq] = s1[3];
        }
    }
}

extern "C" void kernel_launch(void* const* d_in, const int* in_sizes, int n_in,
                              void* d_out, int out_size, void* d_ws, size_t ws_size,
                              hipStream_t stream) {
    const float* x   = (const float*)d_in[0];
    const float* adj = (const float*)d_in[1];
    const float* Wp  = (const float*)d_in[2];
    const float* bp  = (const float*)d_in[3];
    const float* W1  = (const float*)d_in[4];
    const float* a1  = (const float*)d_in[5];
    const float* g1  = (const float*)d_in[6];
    const float* b1  = (const float*)d_in[7];
    const float* W2  = (const float*)d_in[8];
    const float* a2  = (const float*)d_in[9];
    const float* g2  = (const float*)d_in[10];
    const float* b2  = (const float*)d_in[11];
    const int BT = in_sizes[0] / FIN;
    const int blocks = (BT + TPB - 1) / TPB;

    uint8_t* ws = (uint8_t*)d_ws;
    uint16_t* WpT = (uint16_t*)(ws);
    uint16_t* W1T = (uint16_t*)(ws + WS_W1T);
    uint16_t* W2T = (uint16_t*)(ws + WS_W2T);
    float*    vab = (float*)   (ws + WS_VAB);
    float*    bpp = (float*)   (ws + WS_BPP);
    float*    gbp = (float*)   (ws + WS_GBP);

    prep_weights<<<dim3(241), dim3(256), 0, stream>>>(
        Wp, bp, W1, a1, g1, b1, W2, a2, g2, b2, WpT, W1T, W2T, vab, bpp, gbp);
    gat_fused<<<dim3(blocks), dim3(256), 0, stream>>>(
        x, adj, bpp, WpT, W1T, W2T, vab, gbp, (float*)d_out, BT);
}

// Round 18
// 74.845 us; speedup vs baseline: 1.1459x; 1.1459x over previous
//
#include <hip/hip_runtime.h>
#include <math.h>
#include <stdint.h>

#define NN 7
#define HD 128
#define FIN 32
#define TPB 16           // 16 tokens per block; 4 waves, each owns 4 tokens
#define RPW 28           // rows per wave (4 tokens x 7 nodes)
#define LN_EPS 1e-5f
#define ALPHA 0.2f
#define NEG_CONST -9e15f
#define SCALE 0.08838834764831845f  // 128^-0.5

typedef __bf16 bf16x8 __attribute__((ext_vector_type(8)));
typedef float  f32x4  __attribute__((ext_vector_type(4)));

// intra-wave LDS ordering; sched_barrier stops hoisting past the wait (rule #18)
#define FENCE() do { asm volatile("s_waitcnt lgkmcnt(0)" ::: "memory"); \
                     __builtin_amdgcn_sched_barrier(0); } while (0)

__device__ __forceinline__ uint16_t f2bf_u(float f) {
    union { float f; uint32_t u; } v; v.f = f;
    uint32_t r = v.u + 0x7FFFu + ((v.u >> 16) & 1u);  // RNE
    return (uint16_t)(r >> 16);
}
__device__ __forceinline__ uint32_t pack2(float a, float b) {
    return (uint32_t)f2bf_u(a) | ((uint32_t)f2bf_u(b) << 16);
}

// DPP lane-reduce: ctrl must be an ICE -> template parameter
template <int CTRL>
__device__ __forceinline__ float dpp_add(float v) {
    union { float f; int i; } a, r;
    a.f = v;
    r.i = __builtin_amdgcn_update_dpp(a.i, a.i, CTRL, 0xF, 0xF, false);
    return v + r.f;
}
__device__ __forceinline__ float sum16(float v) {
    v = dpp_add<0xB1>(v);    // quad_perm [1,0,3,2] : xor 1
    v = dpp_add<0x4E>(v);    // quad_perm [2,3,0,1] : xor 2
    v = dpp_add<0x124>(v);   // row_ror:4
    v = dpp_add<0x128>(v);   // row_ror:8
    return v;
}

// ws layout (bytes):
//  WpTp[896][32] bf16 @0 | W1Tp[128][128] bf16 @57344 | W2Tp[128][128] bf16 @90112
//  | vabp[2][2][128] f32 @122880 | bpp[896] f32 @124928 | gbp[2][2][128] f32 @128512
#define WS_W1T  57344
#define WS_W2T  90112
#define WS_VAB  122880
#define WS_BPP  124928
#define WS_GBP  128512

__global__ __launch_bounds__(256) void prep_weights(
    const float* __restrict__ Wp, const float* __restrict__ bp,
    const float* __restrict__ W1, const float* __restrict__ a1,
    const float* __restrict__ g1, const float* __restrict__ b1,
    const float* __restrict__ W2, const float* __restrict__ a2,
    const float* __restrict__ g2, const float* __restrict__ b2,
    uint16_t* __restrict__ WpT, uint16_t* __restrict__ W1T,
    uint16_t* __restrict__ W2T, float* __restrict__ vab,
    float* __restrict__ bpp, float* __restrict__ gbp)
{
    const int bid = blockIdx.x, tid = threadIdx.x;
    if (bid < 112) {                 // WpTp[sig(gc)][f] = Wp[f][gc]
        int idx = bid * 256 + tid;
        int gc = idx >> 5, f = idx & 31;
        int gcp = (gc & ~127) | (((gc & 15) << 3) | ((gc & 127) >> 4));
        WpT[gcp * 32 + f] = f2bf_u(Wp[(size_t)f * (NN * HD) + gc]);
    } else if (bid < 176) {          // W1Tp[c][sig(k)] = W1[k][c]
        int idx = (bid - 112) * 256 + tid;
        int c = idx >> 7, k = idx & 127;
        int kp = ((k & 15) << 3) | (k >> 4);
        W1T[c * 128 + kp] = f2bf_u(W1[(size_t)k * HD + c]);
    } else if (bid < 240) {          // W2Tp[c][sig(k)] = W2[k][c]
        int idx = (bid - 176) * 256 + tid;
        int c = idx >> 7, k = idx & 127;
        int kp = ((k & 15) << 3) | (k >> 4);
        W2T[c * 128 + kp] = f2bf_u(W2[(size_t)k * HD + c]);
    } else {
        // vabp[l][which][sig(j)] = sum_o W[j][o]*a[which*128+o]
        for (int d = tid; d < 512; d += 256) {
            int l = d >> 8, which = (d >> 7) & 1, j = d & 127;
            const float* W = l ? W2 : W1;
            const float* a = (l ? a2 : a1) + which * HD;
            const float* row = W + (size_t)j * HD;
            float acc = 0.f;
            #pragma unroll 8
            for (int o = 0; o < HD; o += 4) {
                f32x4 wv = *reinterpret_cast<const f32x4*>(&row[o]);
                acc += wv[0]*a[o] + wv[1]*a[o+1] + wv[2]*a[o+2] + wv[3]*a[o+3];
            }
            int jp = ((j & 15) << 3) | (j >> 4);
            vab[l * 256 + which * 128 + jp] = acc;
        }
        // bpp[sig_g(gc)] = bp[gc]
        for (int gc = tid; gc < NN * HD; gc += 256) {
            int gcp = (gc & ~127) | (((gc & 15) << 3) | ((gc & 127) >> 4));
            bpp[gcp] = bp[gc];
        }
        // gbp[l][{g,b}][sig(c)]
        for (int e = tid; e < 512; e += 256) {
            int l = e >> 8, which = (e >> 7) & 1, c = e & 127;
            const float* src = l ? (which ? b2 : g2) : (which ? b1 : g1);
            int cp = ((c & 15) << 3) | (c >> 4);
            gbp[l * 256 + which * 128 + cp] = src[c];
        }
    }
}

__global__ __launch_bounds__(256, 2) void gat_fused(
    const float* __restrict__ x, const float* __restrict__ adj,
    const float* __restrict__ bpp,
    const uint16_t* __restrict__ WpT, const uint16_t* __restrict__ W1T,
    const uint16_t* __restrict__ W2T, const float* __restrict__ vab,
    const float* __restrict__ gbp,
    float* __restrict__ out, int BT)
{
    // fp32 residual h, sigma-permuted cols; per-wave slice = 28 rows (4 tokens)
    __shared__ __align__(16) float h_s[4][RPW][132];   // 59136 B -> 2 blocks/CU

    const int tid  = threadIdx.x;
    const int lane = tid & 63;
    const int wave = tid >> 6;
    const int frow = lane & 15;
    const int kgrp = lane >> 4;
    const int kb   = kgrp * 8;
    const int t0   = blockIdx.x * TPB;

    // per-lane softmax-row identity: row0 = frow (clamped); tile1 row = 14+row0
    const int row0 = (frow > 13) ? 13 : frow;
    const int tb   = (row0 >= NN) ? 1 : 0;      // token-in-pair
    const int np   = row0 - tb * NN;            // node (same for both tiles)

    uint32_t amask = 0;
    #pragma unroll
    for (int j = 0; j < NN; ++j)
        amask |= (adj[np * NN + j] > 0.f) ? (1u << j) : 0u;

    // ---- B-frag: x for the block's 16 tokens (B col = token = frow) ----
    bf16x8 bx;
    {
        union { bf16x8 v; uint32_t u[4]; } bu;
        bu.u[0] = bu.u[1] = bu.u[2] = bu.u[3] = 0;
        int tok = t0 + frow;
        if (tok < BT) {
            f32x4 xa = *reinterpret_cast<const f32x4*>(&x[(size_t)tok * FIN + kb]);
            f32x4 xb = *reinterpret_cast<const f32x4*>(&x[(size_t)tok * FIN + kb + 4]);
            bu.u[0] = pack2(xa[0], xa[1]);
            bu.u[1] = pack2(xa[2], xa[3]);
            bu.u[2] = pack2(xb[0], xb[1]);
            bu.u[3] = pack2(xb[2], xb[3]);
        }
        bx = bu.v;
    }

    // ---- cooperative projection: 14 tiles/wave, all 16 B-cols used ----
    #pragma unroll 2
    for (int i = 0; i < 14; ++i) {
        int tile = wave * 14 + i;
        bf16x8 av = *reinterpret_cast<const bf16x8*>(WpT + (size_t)(tile * 16 + frow) * FIN + kb);
        f32x4 acc = {0.f, 0.f, 0.f, 0.f};
        acc = __builtin_amdgcn_mfma_f32_16x16x32_bf16(av, bx, acc, 0, 0, 0);
        int tok = t0 + frow;                 // C col = token, C row = out-col'
        if (tok < BT) {
            int gc0 = tile * 16 + kgrp * 4;  // 4 consecutive sigma-cols, same node
            f32x4 bias = *reinterpret_cast<const f32x4*>(&bpp[gc0]);
            f32x4 v = acc + bias;
            int n = gc0 >> 7, kk = gc0 & 127;
            // token frow -> wave slice frow>>2, local row (frow&3)*7+n
            *reinterpret_cast<f32x4*>(&h_s[frow >> 2][(frow & 3) * NN + n][kk]) = v;
        }
    }
    __syncthreads();   // the only block barrier

    for (int l = 0; l < 2; ++l) {
        const uint16_t* __restrict__ WT  = l ? W2T : W1T;
        const float*    __restrict__ vv0 = vab + l * 256;
        const float*    __restrict__ ggp = gbp + l * 256;  // [0..127]=gamma', [128..255]=beta'

        // ---- phase A: f-dots, full 128-dot per lane, vector accumulate ----
        // lanes 0..27: f_src[row=lane]; lanes 32..59: f_dst[row=lane-32]
        float facc;
        {
            int which = lane >> 5;
            int rr = lane & 31; if (rr > RPW - 1) rr = RPW - 1;
            const float* hr = &h_s[wave][rr][0];
            const f32x4* vp = reinterpret_cast<const f32x4*>(vv0 + which * HD);
            f32x4 a0 = {0,0,0,0}, a1 = {0,0,0,0};
            #pragma unroll
            for (int i2 = 0; i2 < 16; ++i2) {
                f32x4 hv0 = *reinterpret_cast<const f32x4*>(hr + i2 * 8);
                f32x4 hv1 = *reinterpret_cast<const f32x4*>(hr + i2 * 8 + 4);
                a0 += hv0 * vp[2 * i2];
                a1 += hv1 * vp[2 * i2 + 1];
            }
            f32x4 a = a0 + a1;
            facc = (a[0] + a[1]) + (a[2] + a[3]);
        }

        // ---- phase B: two softmax rows per lane (row0 tile0, 14+row0 tile1) ----
        float p0[NN], p1[NN];
        {
            float fs0 = __shfl(facc, row0, 64);
            float fs1 = __shfl(facc, 14 + row0, 64);
            float e0[NN], e1[NN];
            float mx0 = -INFINITY, mx1 = -INFINITY;
            #pragma unroll
            for (int j = 0; j < NN; ++j) {
                float fd0 = __shfl(facc, 32 + tb * NN + j, 64);
                float fd1 = __shfl(facc, 32 + 14 + tb * NN + j, 64);
                float v0 = fs0 + fd0, v1 = fs1 + fd1;
                v0 = (v0 > 0.f ? v0 : ALPHA * v0) * SCALE;
                v1 = (v1 > 0.f ? v1 : ALPHA * v1) * SCALE;
                bool ok = (amask >> j) & 1u;
                v0 = ok ? v0 : NEG_CONST;
                v1 = ok ? v1 : NEG_CONST;
                e0[j] = v0; mx0 = fmaxf(mx0, v0);
                e1[j] = v1; mx1 = fmaxf(mx1, v1);
            }
            float s0 = 0.f, s1 = 0.f;
            #pragma unroll
            for (int j = 0; j < NN; ++j) {
                e0[j] = __expf(e0[j] - mx0); s0 += e0[j];
                e1[j] = __expf(e1[j] - mx1); s1 += e1[j];
            }
            float i0 = 1.f / s0, i1 = 1.f / s1;
            #pragma unroll
            for (int j = 0; j < NN; ++j) { p0[j] = e0[j] * i0; p1[j] = e1[j] * i1; }
        }

        // ---- phase C: A-frags for both tiles, vector FMA ----
        bf16x8 avA[4], avB[4];
        #pragma unroll
        for (int ks = 0; ks < 4; ++ks) {
            f32x4 ga0 = {0,0,0,0}, ga1 = {0,0,0,0};
            f32x4 gb0 = {0,0,0,0}, gb1 = {0,0,0,0};
            #pragma unroll
            for (int j = 0; j < NN; ++j) {
                const float* hj = &h_s[wave][tb * NN + j][ks * 32 + kb];
                f32x4 h0 = *reinterpret_cast<const f32x4*>(hj);
                f32x4 h1 = *reinterpret_cast<const f32x4*>(hj + 4);
                float pj = p0[j];
                ga0 += h0 * pj;
                ga1 += h1 * pj;
            }
            #pragma unroll
            for (int j = 0; j < NN; ++j) {
                const float* hj = &h_s[wave][14 + tb * NN + j][ks * 32 + kb];
                f32x4 h0 = *reinterpret_cast<const f32x4*>(hj);
                f32x4 h1 = *reinterpret_cast<const f32x4*>(hj + 4);
                float pj = p1[j];
                gb0 += h0 * pj;
                gb1 += h1 * pj;
            }
            union { bf16x8 v; uint32_t u[4]; } ba, bb;
            ba.u[0] = pack2(ga0[0], ga0[1]); ba.u[1] = pack2(ga0[2], ga0[3]);
            ba.u[2] = pack2(ga1[0], ga1[1]); ba.u[3] = pack2(ga1[2], ga1[3]);
            bb.u[0] = pack2(gb0[0], gb0[1]); bb.u[1] = pack2(gb0[2], gb0[3]);
            bb.u[2] = pack2(gb1[0], gb1[1]); bb.u[3] = pack2(gb1[2], gb1[3]);
            avA[ks] = ba.v; avB[ks] = bb.v;
        }

        // ---- phase D: two GEMM tiles share the B-frag loads (2x amortization) ----
        f32x4 C0[8], C1[8];
        #pragma unroll
        for (int ntl = 0; ntl < 8; ++ntl) {
            const uint16_t* bpg = WT + (size_t)(ntl * 16 + frow) * HD + kb;
            bf16x8 bv0 = *reinterpret_cast<const bf16x8*>(bpg);
            bf16x8 bv1 = *reinterpret_cast<const bf16x8*>(bpg + 32);
            bf16x8 bv2 = *reinterpret_cast<const bf16x8*>(bpg + 64);
            bf16x8 bv3 = *reinterpret_cast<const bf16x8*>(bpg + 96);
            f32x4 a0 = {0,0,0,0}, a1 = {0,0,0,0};
            a0 = __builtin_amdgcn_mfma_f32_16x16x32_bf16(avA[0], bv0, a0, 0, 0, 0);
            a1 = __builtin_amdgcn_mfma_f32_16x16x32_bf16(avB[0], bv0, a1, 0, 0, 0);
            a0 = __builtin_amdgcn_mfma_f32_16x16x32_bf16(avA[1], bv1, a0, 0, 0, 0);
            a1 = __builtin_amdgcn_mfma_f32_16x16x32_bf16(avB[1], bv1, a1, 0, 0, 0);
            a0 = __builtin_amdgcn_mfma_f32_16x16x32_bf16(avA[2], bv2, a0, 0, 0, 0);
            a1 = __builtin_amdgcn_mfma_f32_16x16x32_bf16(avB[2], bv2, a1, 0, 0, 0);
            a0 = __builtin_amdgcn_mfma_f32_16x16x32_bf16(avA[3], bv3, a0, 0, 0, 0);
            a1 = __builtin_amdgcn_mfma_f32_16x16x32_bf16(avB[3], bv3, a1, 0, 0, 0);
            C0[ntl] = a0; C1[ntl] = a1;
        }

        // ---- phase E: LayerNorm + residual; vector reduce + folded epilogue ----
        {
            f32x4 gv0 = *reinterpret_cast<const f32x4*>(ggp + frow * 8);
            f32x4 gv1 = *reinterpret_cast<const f32x4*>(ggp + frow * 8 + 4);
            f32x4 bt0 = *reinterpret_cast<const f32x4*>(ggp + 128 + frow * 8);
            f32x4 bt1 = *reinterpret_cast<const f32x4*>(ggp + 128 + frow * 8 + 4);
            #pragma unroll
            for (int tile = 0; tile < 2; ++tile) {
                const f32x4* C = tile ? C1 : C0;
                const int mbase = tile * 14;
                // vector accumulate across nt: s4[r] = sum, q4[r] = sumsq
                f32x4 s4 = C[0] + C[1];
                f32x4 q4 = C[0]*C[0] + C[1]*C[1];
                #pragma unroll
                for (int nt = 2; nt < 8; ++nt) { s4 += C[nt]; q4 += C[nt]*C[nt]; }
                #pragma unroll
                for (int r = 0; r < 4; ++r) {
                    float s  = sum16(s4[r]);
                    float sq = sum16(q4[r]);
                    float mean = s * (1.f / HD);
                    float var  = sq * (1.f / HD) - mean * mean;
                    float rinv = rsqrtf(var + LN_EPS);
                    int m = kgrp * 4 + r;
                    if (m < 14) {
                        // h += C*coef + off;  coef = rinv*gamma, off = beta - mean*coef
                        f32x4 coef0 = gv0 * rinv, coef1 = gv1 * rinv;
                        f32x4 off0  = bt0 - coef0 * mean;
                        f32x4 off1  = bt1 - coef1 * mean;
                        float* hp = &h_s[wave][mbase + m][frow * 8];
                        f32x4 h0 = *reinterpret_cast<const f32x4*>(hp) + off0;
                        f32x4 h1 = *reinterpret_cast<const f32x4*>(hp + 4) + off1;
                        h0[0] += C[0][r] * coef0[0];
                        h0[1] += C[1][r] * coef0[1];
                        h0[2] += C[2][r] * coef0[2];
                        h0[3] += C[3][r] * coef0[3];
                        h1[0] += C[4][r] * coef1[0];
                        h1[1] += C[5][r] * coef1[1];
                        h1[2] += C[6][r] * coef1[2];
                        h1[3] += C[7][r] * coef1[3];
                        *reinterpret_cast<f32x4*>(hp)     = h0;
                        *reinterpret_cast<f32x4*>(hp + 4) = h1;
                    }
                }
            }
        }
        FENCE();
    }

    // ---- out = mean over nodes; 4 tokens/wave; de-permute on store ----
    {
        int t_o = lane >> 4;            // 0..3
        int cq  = lane & 15;            // sigma col block cq*8..+7
        int tok = t0 + wave * 4 + t_o;
        if (tok < BT) {
            f32x4 s0 = {0,0,0,0}, s1 = {0,0,0,0};
            #pragma unroll
            for (int n = 0; n < NN; ++n) {
                const float* hp = &h_s[wave][t_o * NN + n][cq * 8];
                s0 += *reinterpret_cast<const f32x4*>(hp);
                s1 += *reinterpret_cast<const f32x4*>(hp + 4);
            }
            const float inv7 = 1.f / 7.f;
            s0 *= inv7; s1 *= inv7;
            float* ob = out + (size_t)tok * HD;
            // sigma col cp = cq*8+e  <->  orig c = e*16 + cq
            ob[0*16+cq] = s0[0]; ob[1*16+cq] = s0[1];
            ob[2*16+cq] = s0[2]; ob[3*16+cq] = s0[3];
            ob[4*16+cq] = s1[0]; ob[5*16+cq] = s1[1];
            ob[6*16+cq] = s1[2]; ob[7*16+cq] = s1[3];
        }
    }
}

extern "C" void kernel_launch(void* const* d_in, const int* in_sizes, int n_in,
                              void* d_out, int out_size, void* d_ws, size_t ws_size,
                              hipStream_t stream) {
    const float* x   = (const float*)d_in[0];
    const float* adj = (const float*)d_in[1];
    const float* Wp  = (const float*)d_in[2];
    const float* bp  = (const float*)d_in[3];
    const float* W1  = (const float*)d_in[4];
    const float* a1  = (const float*)d_in[5];
    const float* g1  = (const float*)d_in[6];
    const float* b1  = (const float*)d_in[7];
    const float* W2  = (const float*)d_in[8];
    const float* a2  = (const float*)d_in[9];
    const float* g2  = (const float*)d_in[10];
    const float* b2  = (const float*)d_in[11];
    const int BT = in_sizes[0] / FIN;
    const int blocks = (BT + TPB - 1) / TPB;

    uint8_t* ws = (uint8_t*)d_ws;
    uint16_t* WpT = (uint16_t*)(ws);
    uint16_t* W1T = (uint16_t*)(ws + WS_W1T);
    uint16_t* W2T = (uint16_t*)(ws + WS_W2T);
    float*    vab = (float*)   (ws + WS_VAB);
    float*    bpp = (float*)   (ws + WS_BPP);
    float*    gbp = (float*)   (ws + WS_GBP);

    prep_weights<<<dim3(241), dim3(256), 0, stream>>>(
        Wp, bp, W1, a1, g1, b1, W2, a2, g2, b2, WpT, W1T, W2T, vab, bpp, gbp);
    gat_fused<<<dim3(blocks), dim3(256), 0, stream>>>(
        x, adj, bpp, WpT, W1T, W2T, vab, gbp, (float*)d_out, BT);
}

// Round 19
// 71.609 us; speedup vs baseline: 1.1977x; 1.0452x over previous
//
#include <hip/hip_runtime.h>
#include <math.h>
#include <stdint.h>

#define NN 7
#define HD 128
#define FIN 32
#define TPB 32           // 32 tokens per block; 4 waves, each owns 8 tokens
#define RPW 56           // rows per wave (8 tokens x 7 nodes)
#define LN_EPS 1e-5f
#define ALPHA 0.2f
#define NEG_CONST -9e15f
#define SCALE 0.08838834764831845f  // 128^-0.5

typedef __bf16 bf16x8 __attribute__((ext_vector_type(8)));
typedef float  f32x4  __attribute__((ext_vector_type(4)));

// intra-wave LDS ordering; sched_barrier stops hoisting past the wait (rule #18)
#define FENCE() do { asm volatile("s_waitcnt lgkmcnt(0)" ::: "memory"); \
                     __builtin_amdgcn_sched_barrier(0); } while (0)

__device__ __forceinline__ uint16_t f2bf_u(float f) {
    union { float f; uint32_t u; } v; v.f = f;
    uint32_t r = v.u + 0x7FFFu + ((v.u >> 16) & 1u);  // RNE
    return (uint16_t)(r >> 16);
}
__device__ __forceinline__ uint32_t pack2(float a, float b) {
    return (uint32_t)f2bf_u(a) | ((uint32_t)f2bf_u(b) << 16);
}
__device__ __forceinline__ float bflo(uint32_t u) {
    union { uint32_t q; float f; } v; v.q = u << 16; return v.f;
}
__device__ __forceinline__ float bfhi(uint32_t u) {
    union { uint32_t q; float f; } v; v.q = u & 0xffff0000u; return v.f;
}
__device__ __forceinline__ f32x4 unpk_lo(uint4 h) {
    return (f32x4){bflo(h.x), bfhi(h.x), bflo(h.y), bfhi(h.y)};
}
__device__ __forceinline__ f32x4 unpk_hi(uint4 h) {
    return (f32x4){bflo(h.z), bfhi(h.z), bflo(h.w), bfhi(h.w)};
}

// DPP lane-reduce: ctrl must be an ICE -> template parameter
template <int CTRL>
__device__ __forceinline__ float dpp_add(float v) {
    union { float f; int i; } a, r;
    a.f = v;
    r.i = __builtin_amdgcn_update_dpp(a.i, a.i, CTRL, 0xF, 0xF, false);
    return v + r.f;
}
__device__ __forceinline__ float sum16(float v) {
    v = dpp_add<0xB1>(v);    // quad_perm [1,0,3,2] : xor 1
    v = dpp_add<0x4E>(v);    // quad_perm [2,3,0,1] : xor 2
    v = dpp_add<0x124>(v);   // row_ror:4
    v = dpp_add<0x128>(v);   // row_ror:8
    return v;
}

// ws layout (bytes):
//  WpTp[896][32] bf16 @0 | W1Tp[128][128] bf16 @57344 | W2Tp[128][128] bf16 @90112
//  | vabp[2][2][128] f32 @122880 | bpp[896] f32 @124928 | gbp[2][2][128] f32 @128512
#define WS_W1T  57344
#define WS_W2T  90112
#define WS_VAB  122880
#define WS_BPP  124928
#define WS_GBP  128512

__global__ __launch_bounds__(256) void prep_weights(
    const float* __restrict__ Wp, const float* __restrict__ bp,
    const float* __restrict__ W1, const float* __restrict__ a1,
    const float* __restrict__ g1, const float* __restrict__ b1,
    const float* __restrict__ W2, const float* __restrict__ a2,
    const float* __restrict__ g2, const float* __restrict__ b2,
    uint16_t* __restrict__ WpT, uint16_t* __restrict__ W1T,
    uint16_t* __restrict__ W2T, float* __restrict__ vab,
    float* __restrict__ bpp, float* __restrict__ gbp)
{
    const int bid = blockIdx.x, tid = threadIdx.x;
    if (bid < 112) {                 // WpTp[sig(gc)][f] = Wp[f][gc]
        int idx = bid * 256 + tid;
        int gc = idx >> 5, f = idx & 31;
        int gcp = (gc & ~127) | (((gc & 15) << 3) | ((gc & 127) >> 4));
        WpT[gcp * 32 + f] = f2bf_u(Wp[(size_t)f * (NN * HD) + gc]);
    } else if (bid < 176) {          // W1Tp[c][sig(k)] = W1[k][c]
        int idx = (bid - 112) * 256 + tid;
        int c = idx >> 7, k = idx & 127;
        int kp = ((k & 15) << 3) | (k >> 4);
        W1T[c * 128 + kp] = f2bf_u(W1[(size_t)k * HD + c]);
    } else if (bid < 240) {          // W2Tp[c][sig(k)] = W2[k][c]
        int idx = (bid - 176) * 256 + tid;
        int c = idx >> 7, k = idx & 127;
        int kp = ((k & 15) << 3) | (k >> 4);
        W2T[c * 128 + kp] = f2bf_u(W2[(size_t)k * HD + c]);
    } else {
        // vabp[l][which][sig(j)] = sum_o W[j][o]*a[which*128+o]
        for (int d = tid; d < 512; d += 256) {
            int l = d >> 8, which = (d >> 7) & 1, j = d & 127;
            const float* W = l ? W2 : W1;
            const float* a = (l ? a2 : a1) + which * HD;
            const float* row = W + (size_t)j * HD;
            float acc = 0.f;
            #pragma unroll 8
            for (int o = 0; o < HD; o += 4) {
                f32x4 wv = *reinterpret_cast<const f32x4*>(&row[o]);
                acc += wv[0]*a[o] + wv[1]*a[o+1] + wv[2]*a[o+2] + wv[3]*a[o+3];
            }
            int jp = ((j & 15) << 3) | (j >> 4);
            vab[l * 256 + which * 128 + jp] = acc;
        }
        // bpp[sig_g(gc)] = bp[gc]
        for (int gc = tid; gc < NN * HD; gc += 256) {
            int gcp = (gc & ~127) | (((gc & 15) << 3) | ((gc & 127) >> 4));
            bpp[gcp] = bp[gc];
        }
        // gbp[l][{g,b}][sig(c)]
        for (int e = tid; e < 512; e += 256) {
            int l = e >> 8, which = (e >> 7) & 1, c = e & 127;
            const float* src = l ? (which ? b2 : g2) : (which ? b1 : g1);
            int cp = ((c & 15) << 3) | (c >> 4);
            gbp[l * 256 + which * 128 + cp] = src[c];
        }
    }
}

__global__ __launch_bounds__(256, 2) void gat_fused(
    const float* __restrict__ x, const float* __restrict__ adj,
    const float* __restrict__ bpp,
    const uint16_t* __restrict__ WpT, const uint16_t* __restrict__ W1T,
    const uint16_t* __restrict__ W2T, const float* __restrict__ vab,
    const float* __restrict__ gbp,
    float* __restrict__ out, int BT)
{
    // bf16 residual h, sigma-permuted cols; per-wave slice = 56 rows (8 tokens)
    // 60928 B/block -> 2 blocks/CU = 8 waves/CU; grid 512 blocks = all resident
    __shared__ __align__(16) uint16_t h_s[4][RPW][136];

    const int tid  = threadIdx.x;
    const int lane = tid & 63;
    const int wave = tid >> 6;
    const int frow = lane & 15;
    const int kgrp = lane >> 4;
    const int kb   = kgrp * 8;
    const int t0   = blockIdx.x * TPB;

    // per-lane frag-row identity within each 14-row tile (frow 14,15 -> dup 13)
    const int row0 = (frow > 13) ? 13 : frow;
    const int tb   = (row0 >= NN) ? 1 : 0;      // token-in-pair
    const int np   = row0 - tb * NN;            // node (same for all 4 tiles)

    uint32_t amask = 0;
    #pragma unroll
    for (int j = 0; j < NN; ++j)
        amask |= (adj[np * NN + j] > 0.f) ? (1u << j) : 0u;

    // ---- B-frags: x for tokens 0-15 (bx0) and 16-31 (bx1) ----
    bf16x8 bx0, bx1;
    {
        union { bf16x8 v; uint32_t u[4]; } b0, b1;
        b0.u[0]=b0.u[1]=b0.u[2]=b0.u[3]=0;
        b1.u[0]=b1.u[1]=b1.u[2]=b1.u[3]=0;
        int tokA = t0 + frow;
        if (tokA < BT) {
            f32x4 xa = *reinterpret_cast<const f32x4*>(&x[(size_t)tokA * FIN + kb]);
            f32x4 xb = *reinterpret_cast<const f32x4*>(&x[(size_t)tokA * FIN + kb + 4]);
            b0.u[0] = pack2(xa[0], xa[1]); b0.u[1] = pack2(xa[2], xa[3]);
            b0.u[2] = pack2(xb[0], xb[1]); b0.u[3] = pack2(xb[2], xb[3]);
        }
        int tokB = t0 + 16 + frow;
        if (tokB < BT) {
            f32x4 xa = *reinterpret_cast<const f32x4*>(&x[(size_t)tokB * FIN + kb]);
            f32x4 xb = *reinterpret_cast<const f32x4*>(&x[(size_t)tokB * FIN + kb + 4]);
            b1.u[0] = pack2(xa[0], xa[1]); b1.u[1] = pack2(xa[2], xa[3]);
            b1.u[2] = pack2(xb[0], xb[1]); b1.u[3] = pack2(xb[2], xb[3]);
        }
        bx0 = b0.v; bx1 = b1.v;
    }

    // ---- cooperative projection: 112 items (2 passes x 56 tiles) over 4 waves ----
    for (int idx = wave; idx < 112; idx += 4) {
        int p    = (idx >= 56) ? 1 : 0;
        int tile = idx - p * 56;
        bf16x8 av = *reinterpret_cast<const bf16x8*>(WpT + (size_t)(tile * 16 + frow) * FIN + kb);
        f32x4 acc = {0.f, 0.f, 0.f, 0.f};
        acc = __builtin_amdgcn_mfma_f32_16x16x32_bf16(av, p ? bx1 : bx0, acc, 0, 0, 0);
        int lt  = p * 16 + frow;             // local token 0..31
        int tok = t0 + lt;
        if (tok < BT) {
            int gc0 = tile * 16 + kgrp * 4;  // 4 consecutive sigma-cols, same node
            f32x4 bias = *reinterpret_cast<const f32x4*>(&bpp[gc0]);
            f32x4 v = acc + bias;
            int n = gc0 >> 7, kk = gc0 & 127;
            uint2 uu = { pack2(v[0], v[1]), pack2(v[2], v[3]) };
            // token lt -> wave slice lt>>3, local row (lt&7)*7+n
            *reinterpret_cast<uint2*>(&h_s[lt >> 3][(lt & 7) * NN + n][kk]) = uu;
        }
    }
    __syncthreads();   // the only block barrier

    for (int l = 0; l < 2; ++l) {
        const uint16_t* __restrict__ WT  = l ? W2T : W1T;
        const float*    __restrict__ vv0 = vab + l * 256;
        const float*    __restrict__ ggp = gbp + l * 256;  // [0..127]=gamma', [128..255]=beta'

        // ---- phase A: BOTH f-dots in one h pass; lane -> row = min(lane,55) ----
        float fS, fD;
        {
            int rr = (lane > RPW - 1) ? (RPW - 1) : lane;
            const uint32_t* hr = reinterpret_cast<const uint32_t*>(&h_s[wave][rr][0]);
            const f32x4* vpS = reinterpret_cast<const f32x4*>(vv0);
            const f32x4* vpD = reinterpret_cast<const f32x4*>(vv0 + HD);
            f32x4 s0 = {0,0,0,0}, s1 = {0,0,0,0}, d0 = {0,0,0,0}, d1 = {0,0,0,0};
            #pragma unroll
            for (int i2 = 0; i2 < 16; ++i2) {
                uint4 hv = *reinterpret_cast<const uint4*>(hr + i2 * 4);   // 8 bf16
                f32x4 lo = unpk_lo(hv), hi = unpk_hi(hv);
                s0 += lo * vpS[2 * i2];  s1 += hi * vpS[2 * i2 + 1];
                d0 += lo * vpD[2 * i2];  d1 += hi * vpD[2 * i2 + 1];
            }
            f32x4 sa = s0 + s1, da = d0 + d1;
            fS = (sa[0] + sa[1]) + (sa[2] + sa[3]);
            fD = (da[0] + da[1]) + (da[2] + da[3]);
        }

        // ---- phase B: 4 softmax rows per lane (rows 14q+row0) ----
        float p[4][NN];
        #pragma unroll
        for (int q = 0; q < 4; ++q) {
            float fs = __shfl(fS, 14 * q + row0, 64);
            float e[NN]; float mx = -INFINITY;
            #pragma unroll
            for (int j = 0; j < NN; ++j) {
                float fd = __shfl(fD, 14 * q + tb * NN + j, 64);
                float v = fs + fd;
                v = (v > 0.f ? v : ALPHA * v) * SCALE;
                v = ((amask >> j) & 1u) ? v : NEG_CONST;
                e[j] = v; mx = fmaxf(mx, v);
            }
            float ssum = 0.f;
            #pragma unroll
            for (int j = 0; j < NN; ++j) { e[j] = __expf(e[j] - mx); ssum += e[j]; }
            float inv = 1.f / ssum;
            #pragma unroll
            for (int j = 0; j < NN; ++j) p[q][j] = e[j] * inv;
        }

        // ---- phase C: A-frags for 4 tiles, vector FMA on unpacked bf16 ----
        bf16x8 av4[4][4];   // [tile][ks]
        #pragma unroll
        for (int q = 0; q < 4; ++q) {
            #pragma unroll
            for (int ks = 0; ks < 4; ++ks) {
                f32x4 g0 = {0,0,0,0}, g1 = {0,0,0,0};
                #pragma unroll
                for (int j = 0; j < NN; ++j) {
                    uint4 hv = *reinterpret_cast<const uint4*>(
                        &h_s[wave][14 * q + tb * NN + j][ks * 32 + kb]);
                    float pj = p[q][j];
                    g0 += unpk_lo(hv) * pj;
                    g1 += unpk_hi(hv) * pj;
                }
                union { bf16x8 v; uint32_t u[4]; } bu;
                bu.u[0] = pack2(g0[0], g0[1]); bu.u[1] = pack2(g0[2], g0[3]);
                bu.u[2] = pack2(g1[0], g1[1]); bu.u[3] = pack2(g1[2], g1[3]);
                av4[q][ks] = bu.v;
            }
        }

        // ---- phase D: 4 GEMM tiles share every B-frag load (4x amortization) ----
        f32x4 C[4][8];
        #pragma unroll
        for (int ntl = 0; ntl < 8; ++ntl) {
            const uint16_t* bpg = WT + (size_t)(ntl * 16 + frow) * HD + kb;
            bf16x8 bv0 = *reinterpret_cast<const bf16x8*>(bpg);
            bf16x8 bv1 = *reinterpret_cast<const bf16x8*>(bpg + 32);
            bf16x8 bv2 = *reinterpret_cast<const bf16x8*>(bpg + 64);
            bf16x8 bv3 = *reinterpret_cast<const bf16x8*>(bpg + 96);
            #pragma unroll
            for (int q = 0; q < 4; ++q) {
                f32x4 a = {0,0,0,0};
                a = __builtin_amdgcn_mfma_f32_16x16x32_bf16(av4[q][0], bv0, a, 0, 0, 0);
                a = __builtin_amdgcn_mfma_f32_16x16x32_bf16(av4[q][1], bv1, a, 0, 0, 0);
                a = __builtin_amdgcn_mfma_f32_16x16x32_bf16(av4[q][2], bv2, a, 0, 0, 0);
                a = __builtin_amdgcn_mfma_f32_16x16x32_bf16(av4[q][3], bv3, a, 0, 0, 0);
                C[q][ntl] = a;
            }
        }

        // ---- phase E: LayerNorm + residual for 4 tiles; bf16 b128 RMW ----
        {
            f32x4 gv0 = *reinterpret_cast<const f32x4*>(ggp + frow * 8);
            f32x4 gv1 = *reinterpret_cast<const f32x4*>(ggp + frow * 8 + 4);
            f32x4 bt0 = *reinterpret_cast<const f32x4*>(ggp + 128 + frow * 8);
            f32x4 bt1 = *reinterpret_cast<const f32x4*>(ggp + 128 + frow * 8 + 4);
            #pragma unroll
            for (int q = 0; q < 4; ++q) {
                f32x4 s4 = C[q][0] + C[q][1];
                f32x4 q4 = C[q][0]*C[q][0] + C[q][1]*C[q][1];
                #pragma unroll
                for (int nt = 2; nt < 8; ++nt) { s4 += C[q][nt]; q4 += C[q][nt]*C[q][nt]; }
                #pragma unroll
                for (int r = 0; r < 4; ++r) {
                    float s  = sum16(s4[r]);
                    float sq = sum16(q4[r]);
                    float mean = s * (1.f / HD);
                    float var  = sq * (1.f / HD) - mean * mean;
                    float rinv = rsqrtf(var + LN_EPS);
                    int m = kgrp * 4 + r;
                    if (m < 14) {
                        f32x4 coef0 = gv0 * rinv, coef1 = gv1 * rinv;
                        f32x4 off0  = bt0 - coef0 * mean;
                        f32x4 off1  = bt1 - coef1 * mean;
                        uint16_t* hp = &h_s[wave][14 * q + m][frow * 8];
                        uint4 hold = *reinterpret_cast<const uint4*>(hp);
                        f32x4 h0 = unpk_lo(hold) + off0;
                        f32x4 h1 = unpk_hi(hold) + off1;
                        h0[0] += C[q][0][r] * coef0[0];
                        h0[1] += C[q][1][r] * coef0[1];
                        h0[2] += C[q][2][r] * coef0[2];
                        h0[3] += C[q][3][r] * coef0[3];
                        h1[0] += C[q][4][r] * coef1[0];
                        h1[1] += C[q][5][r] * coef1[1];
                        h1[2] += C[q][6][r] * coef1[2];
                        h1[3] += C[q][7][r] * coef1[3];
                        uint4 w;
                        w.x = pack2(h0[0], h0[1]); w.y = pack2(h0[2], h0[3]);
                        w.z = pack2(h1[0], h1[1]); w.w = pack2(h1[2], h1[3]);
                        *reinterpret_cast<uint4*>(hp) = w;
                    }
                }
            }
        }
        FENCE();
    }

    // ---- out = mean over nodes; 8 tokens/wave; de-permute on store ----
    {
        int t_o = lane >> 3;            // 0..7 token within wave
        int cb  = lane & 7;             // sigma col block cb*16 .. +15
        int tok = t0 + wave * 8 + t_o;
        if (tok < BT) {
            f32x4 s[4] = {{0,0,0,0},{0,0,0,0},{0,0,0,0},{0,0,0,0}};
            #pragma unroll
            for (int n = 0; n < NN; ++n) {
                const uint16_t* hp = &h_s[wave][t_o * NN + n][cb * 16];
                uint4 h0 = *reinterpret_cast<const uint4*>(hp);
                uint4 h1 = *reinterpret_cast<const uint4*>(hp + 8);
                s[0] += unpk_lo(h0); s[1] += unpk_hi(h0);
                s[2] += unpk_lo(h1); s[3] += unpk_hi(h1);
            }
            const float inv7 = 1.f / 7.f;
            float* ob = out + (size_t)tok * HD;
            // sigma col cp = cb*16 + u*4 + e  <->  orig c = (cp&7)*16 + (cp>>3)
            #pragma unroll
            for (int u = 0; u < 4; ++u) {
                #pragma unroll
                for (int e = 0; e < 4; ++e) {
                    int cp = cb * 16 + u * 4 + e;
                    ob[(cp & 7) * 16 + (cp >> 3)] = s[u][e] * inv7;
                }
            }
        }
    }
}

extern "C" void kernel_launch(void* const* d_in, const int* in_sizes, int n_in,
                              void* d_out, int out_size, void* d_ws, size_t ws_size,
                              hipStream_t stream) {
    const float* x   = (const float*)d_in[0];
    const float* adj = (const float*)d_in[1];
    const float* Wp  = (const float*)d_in[2];
    const float* bp  = (const float*)d_in[3];
    const float* W1  = (const float*)d_in[4];
    const float* a1  = (const float*)d_in[5];
    const float* g1  = (const float*)d_in[6];
    const float* b1  = (const float*)d_in[7];
    const float* W2  = (const float*)d_in[8];
    const float* a2  = (const float*)d_in[9];
    const float* g2  = (const float*)d_in[10];
    const float* b2  = (const float*)d_in[11];
    const int BT = in_sizes[0] / FIN;
    const int blocks = (BT + TPB - 1) / TPB;

    uint8_t* ws = (uint8_t*)d_ws;
    uint16_t* WpT = (uint16_t*)(ws);
    uint16_t* W1T = (uint16_t*)(ws + WS_W1T);
    uint16_t* W2T = (uint16_t*)(ws + WS_W2T);
    float*    vab = (float*)   (ws + WS_VAB);
    float*    bpp = (float*)   (ws + WS_BPP);
    float*    gbp = (float*)   (ws + WS_GBP);

    prep_weights<<<dim3(241), dim3(256), 0, stream>>>(
        Wp, bp, W1, a1, g1, b1, W2, a2, g2, b2, WpT, W1T, W2T, vab, bpp, gbp);
    gat_fused<<<dim3(blocks), dim3(256), 0, stream>>>(
        x, adj, bpp, WpT, W1T, W2T, vab, gbp, (float*)d_out, BT);
}